// Round 8
// baseline (145.744 us; speedup 1.0000x reference)
//
#include <hip/hip_runtime.h>
#include <hip/hip_bf16.h>

#define NN 50000
#define NE 800000
#define D 128

#define RPB 50            // rows per bucket
#define NB 1000           // NN / RPB
#define CAP 1024          // record capacity per bucket (mean 800)
#define TILE 2048         // edges per bin block
#define NBIN 391          // ceil(NE/TILE)
#define AROWS 64          // padded rows (4 mtiles x 16)
#define TSTR 136          // bf16 tile row stride: 272B, 16B-aligned

#define CASTB 1563        // ceil(800000 / 512) uint4-casts of x
#define PACKB 4           // 2048 threads / 512

// ws layout in dwords
#define XH_OFF   0                   // x_h bf16: 3,200,000 dwords
#define WF_OFF   3200000             // Wf: 8192 dwords
#define CUR_OFF  3208192             // 1024 cursors
#define REC_OFF  3209216             // records: NB*CAP int2

typedef short bf16x8 __attribute__((ext_vector_type(8)));
typedef float f32x4 __attribute__((ext_vector_type(4)));

__device__ inline unsigned short f2bf_u(float f) {
    __hip_bfloat16 h = __float2bfloat16(f);   // RNE
    return __builtin_bit_cast(unsigned short, h);
}
__device__ inline unsigned pack2(float a, float b) {
    return (unsigned)f2bf_u(a) | ((unsigned)f2bf_u(b) << 16);
}
__device__ inline void acc8(float* acc, uint4 v, float w) {
    unsigned dw[4] = {v.x, v.y, v.z, v.w};
    #pragma unroll
    for (int i = 0; i < 4; ++i) {
        float lo = __int_as_float((int)(dw[i] << 16));
        float hi = __int_as_float((int)(dw[i] & 0xffff0000u));
        acc[2 * i]     += w * lo;
        acc[2 * i + 1] += w * hi;
    }
}

// ---------------------------------------------------------------------------
// 1) fused grid: cast x->bf16 | pack W B-frag | bin edges into 1000 buckets.
//    cursor[] zeroed by prior hipMemsetAsync.
// ---------------------------------------------------------------------------
__global__ __launch_bounds__(512) void cast_bin_kernel(
    const float* __restrict__ x, const float* __restrict__ W,
    const int* __restrict__ erow, const int* __restrict__ ecol,
    const float* __restrict__ ew,
    unsigned* __restrict__ x_h4, unsigned short* __restrict__ Wf,
    int* __restrict__ cursor, int2* __restrict__ recs)
{
    __shared__ int  lhist[1024];
    __shared__ int  lexcl[1024];
    __shared__ int  lbase[1024];
    __shared__ int  wsum[8];
    __shared__ int  wexcl[8];
    __shared__ int2 stag[TILE];

    int b = blockIdx.x;
    int t = threadIdx.x;

    if (b < CASTB) {
        int idx = b * 512 + t;                 // [0, 800000)
        if (idx < 800000) {
            const float4* x4 = (const float4*)x;
            float4 v0 = x4[idx * 2];
            float4 v1 = x4[idx * 2 + 1];
            uint4 o;
            o.x = pack2(v0.x, v0.y);
            o.y = pack2(v0.z, v0.w);
            o.z = pack2(v1.x, v1.y);
            o.w = pack2(v1.z, v1.w);
            ((uint4*)x_h4)[idx] = o;
        }
        return;
    }
    if (b < CASTB + PACKB) {
        // Wf[(nt*4+c)*64+lane] : element j -> W[c*32+(lane>>4)*8+j][nt*16+(lane&15)]
        int flat = (b - CASTB) * 512 + t;      // [0, 2048)
        int lane = flat & 63;
        int c    = (flat >> 6) & 3;
        int nt   = flat >> 8;
        int col  = nt * 16 + (lane & 15);
        int kb   = c * 32 + (lane >> 4) * 8;
        unsigned d[4];
        #pragma unroll
        for (int jj = 0; jj < 4; ++jj) {
            float a  = W[(kb + 2 * jj) * D + col];
            float bb = W[(kb + 2 * jj + 1) * D + col];
            d[jj] = pack2(a, bb);
        }
        uint4 o; o.x = d[0]; o.y = d[1]; o.z = d[2]; o.w = d[3];
        ((uint4*)Wf)[flat] = o;
        return;
    }

    // ---- bin branch: 2048 edges, one int4 group per thread ----
    int base = (b - CASTB - PACKB) * TILE;
    int cnt = NE - base; if (cnt > TILE) cnt = TILE;

    lhist[t] = 0;
    lhist[t + 512] = 0;
    __syncthreads();

    int4 r, c; float4 w;
    int i4 = (base >> 2) + t;
    bool val = (i4 * 4) < NE;
    if (val) {
        r = ((const int4*)erow)[i4];
        c = ((const int4*)ecol)[i4];
        w = ((const float4*)ew)[i4];
        atomicAdd(&lhist[(unsigned)r.x / RPB], 1);
        atomicAdd(&lhist[(unsigned)r.y / RPB], 1);
        atomicAdd(&lhist[(unsigned)r.z / RPB], 1);
        atomicAdd(&lhist[(unsigned)r.w / RPB], 1);
    }
    __syncthreads();

    // scan 1024 bins: 2 bins/thread, wave-shuffle scan + 8-wave combine
    int a0 = lhist[2 * t], a1 = lhist[2 * t + 1];
    int s = a0 + a1;
    int lane = t & 63, wv = t >> 6;
    #pragma unroll
    for (int off = 1; off < 64; off <<= 1) {
        int v = __shfl_up(s, off, 64);
        if (lane >= off) s += v;
    }
    if (lane == 63) wsum[wv] = s;
    __syncthreads();
    if (t < 8) {
        int e = 0;
        for (int i = 0; i < t; ++i) e += wsum[i];
        wexcl[t] = e;
    }
    __syncthreads();
    int exclT = s + wexcl[wv] - (a0 + a1);
    lexcl[2 * t]     = exclT;
    lexcl[2 * t + 1] = exclT + a0;
    lbase[2 * t]     = a0 ? atomicAdd(&cursor[2 * t], a0) : 0;
    lbase[2 * t + 1] = a1 ? atomicAdd(&cursor[2 * t + 1], a1) : 0;
    lhist[2 * t]     = exclT;          // rank cursor
    lhist[2 * t + 1] = exclT + a0;
    __syncthreads();

    if (val) {
        int rr[4] = {r.x, r.y, r.z, r.w};
        int cc[4] = {c.x, c.y, c.z, c.w};
        float wwv[4] = {w.x, w.y, w.z, w.w};
        #pragma unroll
        for (int j = 0; j < 4; ++j) {
            int bk = (unsigned)rr[j] / RPB;
            int rank = atomicAdd(&lhist[bk], 1);
            int2 rec;
            rec.x = (rr[j] << 16) | cc[j];
            rec.y = __float_as_int(wwv[j]);
            stag[rank] = rec;
        }
    }
    __syncthreads();

    #pragma unroll
    for (int k = 0; k < 4; ++k) {
        int i = t + k * 512;
        if (i < cnt) {
            int2 rec = stag[i];
            int bk = (((unsigned)rec.x) >> 16) / RPB;
            int pos = lbase[bk] + (i - lexcl[bk]);
            if (pos < CAP)
                recs[(size_t)bk * CAP + pos] = rec;
        }
    }
}

// ---------------------------------------------------------------------------
// 2) per-bucket (50 rows): records -> LDS counting-sort by row -> dual-row
//    register gather (16 lanes/node, 2 rows interleaved for MLP) ->
//    bf16 LDS tile -> MFMA GEMM + bias -> out.
// ---------------------------------------------------------------------------
__global__ __launch_bounds__(512) void gat_gemm_kernel(
    const unsigned short* __restrict__ x_h, const int2* __restrict__ recs,
    const int* __restrict__ cursor, const unsigned short* __restrict__ Wf,
    const float* __restrict__ bias, float* __restrict__ out)
{
    __shared__ int2 srec[CAP];                                   // 8 KB
    __shared__ __align__(16) unsigned short tile[AROWS * TSTR];  // 17.4 KB
    __shared__ int rowstart[64];
    __shared__ int rowcur[64];

    int t = threadIdx.x;
    int b = blockIdx.x;
    int cnt = cursor[b];
    if (cnt > CAP) cnt = CAP;
    int rb = b * RPB;
    const int2* my = recs + (size_t)b * CAP;

    if (t < 64) rowcur[t] = 0;
    __syncthreads();

    // single global pass: records -> registers, histogram
    int2 r0, r1;
    bool v0 = t < cnt, v1 = t + 512 < cnt;
    if (v0) r0 = my[t];
    if (v1) r1 = my[t + 512];
    if (v0) atomicAdd(&rowcur[(((unsigned)r0.x) >> 16) - rb], 1);
    if (v1) atomicAdd(&rowcur[(((unsigned)r1.x) >> 16) - rb], 1);
    __syncthreads();

    // exclusive scan of 64 row counts: wave 0 shuffle scan (no barrier loop)
    if (t < 64) {
        int cth = rowcur[t];
        int s = cth;
        #pragma unroll
        for (int off = 1; off < 64; off <<= 1) {
            int v = __shfl_up(s, off, 64);
            if (t >= off) s += v;
        }
        int ex = s - cth;     // rows 50..63 have count 0, so ex(50) == cnt
        rowstart[t] = ex;
        rowcur[t] = ex;
    }
    __syncthreads();

    // rank + scatter into srec (sorted by row)
    if (v0) srec[atomicAdd(&rowcur[(((unsigned)r0.x) >> 16) - rb], 1)] = r0;
    if (v1) srec[atomicAdd(&rowcur[(((unsigned)r1.x) >> 16) - rb], 1)] = r1;
    __syncthreads();

    // gather: 16 lanes per node; two rows per group interleaved (2x MLP)
    int q = t & 15;
    int grp = t >> 4;                  // 0..31
    int rlA = grp;                     // rows 0..31
    int rlB = 32 + grp;                // rows 32..49 when grp < 18
    const uint4* xv = (const uint4*)x_h;   // one x row = 16 uint4

    int pA = rowstart[rlA], eA = rowstart[rlA + 1];
    int pB = 0, eB = 0;
    bool hasB = (rlB < RPB);
    if (hasB) { pB = rowstart[rlB]; eB = rowstart[rlB + 1]; }

    float accA[8] = {}, accB[8] = {};
    while (pA + 2 <= eA && pB + 2 <= eB) {
        int2 ea0 = srec[pA], ea1 = srec[pA + 1];
        int2 eb0 = srec[pB], eb1 = srec[pB + 1];
        uint4 va0 = xv[(size_t)(ea0.x & 0xffff) * 16 + q];
        uint4 va1 = xv[(size_t)(ea1.x & 0xffff) * 16 + q];
        uint4 vb0 = xv[(size_t)(eb0.x & 0xffff) * 16 + q];
        uint4 vb1 = xv[(size_t)(eb1.x & 0xffff) * 16 + q];
        acc8(accA, va0, __int_as_float(ea0.y));
        acc8(accA, va1, __int_as_float(ea1.y));
        acc8(accB, vb0, __int_as_float(eb0.y));
        acc8(accB, vb1, __int_as_float(eb1.y));
        pA += 2; pB += 2;
    }
    // drain A
    for (; pA + 4 <= eA; pA += 4) {
        int2 e0 = srec[pA], e1 = srec[pA + 1], e2 = srec[pA + 2], e3 = srec[pA + 3];
        uint4 w0 = xv[(size_t)(e0.x & 0xffff) * 16 + q];
        uint4 w1 = xv[(size_t)(e1.x & 0xffff) * 16 + q];
        uint4 w2 = xv[(size_t)(e2.x & 0xffff) * 16 + q];
        uint4 w3 = xv[(size_t)(e3.x & 0xffff) * 16 + q];
        acc8(accA, w0, __int_as_float(e0.y));
        acc8(accA, w1, __int_as_float(e1.y));
        acc8(accA, w2, __int_as_float(e2.y));
        acc8(accA, w3, __int_as_float(e3.y));
    }
    for (; pA < eA; ++pA) {
        int2 e = srec[pA];
        uint4 w = xv[(size_t)(e.x & 0xffff) * 16 + q];
        acc8(accA, w, __int_as_float(e.y));
    }
    // drain B
    for (; pB + 4 <= eB; pB += 4) {
        int2 e0 = srec[pB], e1 = srec[pB + 1], e2 = srec[pB + 2], e3 = srec[pB + 3];
        uint4 w0 = xv[(size_t)(e0.x & 0xffff) * 16 + q];
        uint4 w1 = xv[(size_t)(e1.x & 0xffff) * 16 + q];
        uint4 w2 = xv[(size_t)(e2.x & 0xffff) * 16 + q];
        uint4 w3 = xv[(size_t)(e3.x & 0xffff) * 16 + q];
        acc8(accB, w0, __int_as_float(e0.y));
        acc8(accB, w1, __int_as_float(e1.y));
        acc8(accB, w2, __int_as_float(e2.y));
        acc8(accB, w3, __int_as_float(e3.y));
    }
    for (; pB < eB; ++pB) {
        int2 e = srec[pB];
        uint4 w = xv[(size_t)(e.x & 0xffff) * 16 + q];
        acc8(accB, w, __int_as_float(e.y));
    }
    {
        uint4 o;
        o.x = pack2(accA[0], accA[1]);
        o.y = pack2(accA[2], accA[3]);
        o.z = pack2(accA[4], accA[5]);
        o.w = pack2(accA[6], accA[7]);
        *(uint4*)&tile[rlA * TSTR + q * 8] = o;
        if (hasB) {
            uint4 p;
            p.x = pack2(accB[0], accB[1]);
            p.y = pack2(accB[2], accB[3]);
            p.z = pack2(accB[4], accB[5]);
            p.w = pack2(accB[6], accB[7]);
            *(uint4*)&tile[rlB * TSTR + q * 8] = p;
        }
    }
    __syncthreads();

    // MFMA tail: 8 waves x 16-col ntile; rows 50..63 garbage but D row m
    // depends only on A row m; stores guarded.
    int wave = t >> 6, lane = t & 63;
    int m = lane & 15, quad = lane >> 4;
    const bf16x8* bp = (const bf16x8*)Wf;
    bf16x8 bfr[4];
    #pragma unroll
    for (int c = 0; c < 4; ++c) bfr[c] = bp[(wave * 4 + c) * 64 + lane];
    float bcol = bias[wave * 16 + m];

    #pragma unroll
    for (int mt = 0; mt < 4; ++mt) {
        f32x4 acc = {0.f, 0.f, 0.f, 0.f};
        #pragma unroll
        for (int c = 0; c < 4; ++c) {
            bf16x8 afr = *(const bf16x8*)&tile[(mt * 16 + m) * TSTR + c * 32 + quad * 8];
            acc = __builtin_amdgcn_mfma_f32_16x16x32_bf16(afr, bfr[c], acc, 0, 0, 0);
        }
        #pragma unroll
        for (int r = 0; r < 4; ++r) {
            int lr = mt * 16 + quad * 4 + r;
            int grow = rb + lr;
            if (lr < RPB && grow < NN)
                out[(size_t)grow * D + wave * 16 + m] = acc[r] + bcol;
        }
    }
}

extern "C" void kernel_launch(void* const* d_in, const int* in_sizes, int n_in,
                              void* d_out, int out_size, void* d_ws, size_t ws_size,
                              hipStream_t stream) {
    const float* x    = (const float*)d_in[0];
    const float* W    = (const float*)d_in[1];
    const float* bias = (const float*)d_in[2];
    const float* ew   = (const float*)d_in[3];
    const int*   erow = (const int*)d_in[4];
    const int*   ecol = (const int*)d_in[5];
    float* out = (float*)d_out;

    unsigned* ws_u = (unsigned*)d_ws;
    unsigned*        x_h4   = ws_u + XH_OFF;
    unsigned short*  x_h    = (unsigned short*)x_h4;
    unsigned short*  Wf     = (unsigned short*)(ws_u + WF_OFF);
    int*             cursor = (int*)(ws_u + CUR_OFF);
    int2*            recs   = (int2*)(ws_u + REC_OFF);

    hipMemsetAsync(cursor, 0, 1024 * sizeof(int), stream);
    cast_bin_kernel<<<CASTB + PACKB + NBIN, 512, 0, stream>>>(
        x, W, erow, ecol, ew, x_h4, Wf, cursor, recs);
    gat_gemm_kernel<<<NB, 512, 0, stream>>>(x_h, recs, cursor, Wf, bias, out);
}

// Round 9
// 136.852 us; speedup vs baseline: 1.0650x; 1.0650x over previous
//
#include <hip/hip_runtime.h>
#include <hip/hip_bf16.h>

#define NN 50000
#define NE 800000
#define D 128

#define RPB 50            // rows per bucket
#define NB 1000           // NN / RPB
#define CAP 1024          // record capacity per bucket (mean 800, +8 sigma)
#define TILE 4096         // edges per bin block (4-record avg runs per bucket)
#define NBIN 196          // ceil(NE/TILE)
#define AROWS 64          // padded rows (4 mtiles x 16)
#define TSTR 136          // bf16 tile row stride: 272B, 16B-aligned

#define CASTB 1563        // ceil(800000 / 512) uint4-casts of x
#define PACKB 4           // 2048 threads / 512

// ws layout in dwords
#define XH_OFF   0                   // x_h bf16: 3,200,000 dwords
#define WF_OFF   3200000             // Wf: 8192 dwords
#define CUR_OFF  3208192             // 1024 cursors
#define REC_OFF  3209216             // records: NB*CAP int2

typedef short bf16x8 __attribute__((ext_vector_type(8)));
typedef float f32x4 __attribute__((ext_vector_type(4)));

__device__ inline unsigned short f2bf_u(float f) {
    __hip_bfloat16 h = __float2bfloat16(f);   // RNE
    return __builtin_bit_cast(unsigned short, h);
}
__device__ inline unsigned pack2(float a, float b) {
    return (unsigned)f2bf_u(a) | ((unsigned)f2bf_u(b) << 16);
}
__device__ inline void acc8(float* acc, uint4 v, float w) {
    unsigned dw[4] = {v.x, v.y, v.z, v.w};
    #pragma unroll
    for (int i = 0; i < 4; ++i) {
        float lo = __int_as_float((int)(dw[i] << 16));
        float hi = __int_as_float((int)(dw[i] & 0xffff0000u));
        acc[2 * i]     += w * lo;
        acc[2 * i + 1] += w * hi;
    }
}

// ---------------------------------------------------------------------------
// 1) fused grid: cast x->bf16 | pack W B-frag | bin edges into 1000 buckets
//    via LDS staging (TILE=4096 keeps global record runs ~4 recs/bucket).
//    cursor[] zeroed by prior hipMemsetAsync.
// ---------------------------------------------------------------------------
__global__ __launch_bounds__(512) void cast_bin_kernel(
    const float* __restrict__ x, const float* __restrict__ W,
    const int* __restrict__ erow, const int* __restrict__ ecol,
    const float* __restrict__ ew,
    unsigned* __restrict__ x_h4, unsigned short* __restrict__ Wf,
    int* __restrict__ cursor, int2* __restrict__ recs)
{
    __shared__ int  lhist[1024];
    __shared__ int  lexcl[1024];
    __shared__ int  lbase[1024];
    __shared__ int  wsum[8];
    __shared__ int  wexcl[8];
    __shared__ int2 stag[TILE];

    int b = blockIdx.x;
    int t = threadIdx.x;

    if (b < CASTB) {
        int idx = b * 512 + t;                 // [0, 800000)
        if (idx < 800000) {
            const float4* x4 = (const float4*)x;
            float4 v0 = x4[idx * 2];
            float4 v1 = x4[idx * 2 + 1];
            uint4 o;
            o.x = pack2(v0.x, v0.y);
            o.y = pack2(v0.z, v0.w);
            o.z = pack2(v1.x, v1.y);
            o.w = pack2(v1.z, v1.w);
            ((uint4*)x_h4)[idx] = o;
        }
        return;
    }
    if (b < CASTB + PACKB) {
        // Wf[(nt*4+c)*64+lane] : element j -> W[c*32+(lane>>4)*8+j][nt*16+(lane&15)]
        int flat = (b - CASTB) * 512 + t;      // [0, 2048)
        int lane = flat & 63;
        int c    = (flat >> 6) & 3;
        int nt   = flat >> 8;
        int col  = nt * 16 + (lane & 15);
        int kb   = c * 32 + (lane >> 4) * 8;
        unsigned d[4];
        #pragma unroll
        for (int jj = 0; jj < 4; ++jj) {
            float a  = W[(kb + 2 * jj) * D + col];
            float bb = W[(kb + 2 * jj + 1) * D + col];
            d[jj] = pack2(a, bb);
        }
        uint4 o; o.x = d[0]; o.y = d[1]; o.z = d[2]; o.w = d[3];
        ((uint4*)Wf)[flat] = o;
        return;
    }

    // ---- bin branch: 4096 edges, two int4 groups per thread ----
    int base = (b - CASTB - PACKB) * TILE;
    int cnt = NE - base; if (cnt > TILE) cnt = TILE;

    lhist[t] = 0;
    lhist[t + 512] = 0;
    __syncthreads();

    int4 r[2], c[2]; float4 w[2]; bool val[2];
    #pragma unroll
    for (int g = 0; g < 2; ++g) {
        int i4 = (base >> 2) + t + g * 512;
        val[g] = (i4 * 4) < NE && (i4 * 4) < (base + TILE);
        if (val[g]) {
            r[g] = ((const int4*)erow)[i4];
            c[g] = ((const int4*)ecol)[i4];
            w[g] = ((const float4*)ew)[i4];
        }
    }
    #pragma unroll
    for (int g = 0; g < 2; ++g) {
        if (val[g]) {
            atomicAdd(&lhist[(unsigned)r[g].x / RPB], 1);
            atomicAdd(&lhist[(unsigned)r[g].y / RPB], 1);
            atomicAdd(&lhist[(unsigned)r[g].z / RPB], 1);
            atomicAdd(&lhist[(unsigned)r[g].w / RPB], 1);
        }
    }
    __syncthreads();

    // scan 1024 bins: 2 bins/thread, wave shuffle scan + 8-wave combine
    int a0 = lhist[2 * t], a1 = lhist[2 * t + 1];
    int s = a0 + a1;
    int lane = t & 63, wv = t >> 6;
    #pragma unroll
    for (int off = 1; off < 64; off <<= 1) {
        int v = __shfl_up(s, off, 64);
        if (lane >= off) s += v;
    }
    if (lane == 63) wsum[wv] = s;
    __syncthreads();
    if (t < 8) {
        int e = 0;
        for (int i = 0; i < t; ++i) e += wsum[i];
        wexcl[t] = e;
    }
    __syncthreads();
    int exclT = s + wexcl[wv] - (a0 + a1);
    lexcl[2 * t]     = exclT;
    lexcl[2 * t + 1] = exclT + a0;
    lbase[2 * t]     = a0 ? atomicAdd(&cursor[2 * t], a0) : 0;
    lbase[2 * t + 1] = a1 ? atomicAdd(&cursor[2 * t + 1], a1) : 0;
    lhist[2 * t]     = exclT;          // rank cursor
    lhist[2 * t + 1] = exclT + a0;
    __syncthreads();

    #pragma unroll
    for (int g = 0; g < 2; ++g) {
        if (val[g]) {
            int rr[4] = {r[g].x, r[g].y, r[g].z, r[g].w};
            int cc[4] = {c[g].x, c[g].y, c[g].z, c[g].w};
            float wwv[4] = {w[g].x, w[g].y, w[g].z, w[g].w};
            #pragma unroll
            for (int j = 0; j < 4; ++j) {
                int bk = (unsigned)rr[j] / RPB;
                int rank = atomicAdd(&lhist[bk], 1);
                int2 rec;
                rec.x = (rr[j] << 16) | cc[j];
                rec.y = __float_as_int(wwv[j]);
                stag[rank] = rec;
            }
        }
    }
    __syncthreads();

    #pragma unroll
    for (int k = 0; k < 8; ++k) {
        int i = t + k * 512;
        if (i < cnt) {
            int2 rec = stag[i];
            int bk = (((unsigned)rec.x) >> 16) / RPB;
            int pos = lbase[bk] + (i - lexcl[bk]);
            if (pos < CAP)
                recs[(size_t)bk * CAP + pos] = rec;
        }
    }
}

// ---------------------------------------------------------------------------
// 2) per-bucket (50 rows): records -> LDS counting-sort by row -> single-row
//    register gather (16 lanes/node, unroll 8) -> bf16 LDS tile ->
//    MFMA GEMM + bias -> out. No float atomics.
// ---------------------------------------------------------------------------
__global__ __launch_bounds__(512) void gat_gemm_kernel(
    const unsigned short* __restrict__ x_h, const int2* __restrict__ recs,
    const int* __restrict__ cursor, const unsigned short* __restrict__ Wf,
    const float* __restrict__ bias, float* __restrict__ out)
{
    __shared__ int2 srec[CAP];                                   // 8 KB
    __shared__ __align__(16) unsigned short tile[AROWS * TSTR];  // 17.4 KB
    __shared__ int rowstart[64];
    __shared__ int rowcur[64];

    int t = threadIdx.x;
    int b = blockIdx.x;
    int cnt = cursor[b];
    if (cnt > CAP) cnt = CAP;
    int rb = b * RPB;
    const int2* my = recs + (size_t)b * CAP;

    if (t < 64) rowcur[t] = 0;
    __syncthreads();

    // single global pass: records -> registers, histogram
    int2 r0, r1;
    bool v0 = t < cnt, v1 = t + 512 < cnt;
    if (v0) r0 = my[t];
    if (v1) r1 = my[t + 512];
    if (v0) atomicAdd(&rowcur[(((unsigned)r0.x) >> 16) - rb], 1);
    if (v1) atomicAdd(&rowcur[(((unsigned)r1.x) >> 16) - rb], 1);
    __syncthreads();

    // exclusive scan of 64 row counts: wave 0 shuffle scan
    if (t < 64) {
        int cth = rowcur[t];
        int s = cth;
        #pragma unroll
        for (int off = 1; off < 64; off <<= 1) {
            int v = __shfl_up(s, off, 64);
            if (t >= off) s += v;
        }
        int ex = s - cth;
        rowstart[t] = ex;
        rowcur[t] = ex;
    }
    __syncthreads();

    // rank + scatter into srec (sorted by row)
    if (v0) srec[atomicAdd(&rowcur[(((unsigned)r0.x) >> 16) - rb], 1)] = r0;
    if (v1) srec[atomicAdd(&rowcur[(((unsigned)r1.x) >> 16) - rb], 1)] = r1;
    __syncthreads();

    // gather: 16 lanes per node, 32 nodes concurrently, unroll 8
    int q = t & 15;
    int grp = t >> 4;
    const uint4* xv = (const uint4*)x_h;   // one x row = 16 uint4
    #pragma unroll
    for (int it = 0; it < 2; ++it) {
        int rl = it * 32 + grp;
        if (rl < RPB) {
            int p = rowstart[rl];
            int p1 = (rl + 1 <= RPB) ? ((rl + 1 == RPB) ? cnt : rowstart[rl + 1]) : cnt;
            float acc[8] = {};
            for (; p + 8 <= p1; p += 8) {
                int2 e0 = srec[p],     e1 = srec[p + 1], e2 = srec[p + 2], e3 = srec[p + 3];
                int2 e4 = srec[p + 4], e5 = srec[p + 5], e6 = srec[p + 6], e7 = srec[p + 7];
                uint4 w0 = xv[(size_t)(e0.x & 0xffff) * 16 + q];
                uint4 w1 = xv[(size_t)(e1.x & 0xffff) * 16 + q];
                uint4 w2 = xv[(size_t)(e2.x & 0xffff) * 16 + q];
                uint4 w3 = xv[(size_t)(e3.x & 0xffff) * 16 + q];
                uint4 w4 = xv[(size_t)(e4.x & 0xffff) * 16 + q];
                uint4 w5 = xv[(size_t)(e5.x & 0xffff) * 16 + q];
                uint4 w6 = xv[(size_t)(e6.x & 0xffff) * 16 + q];
                uint4 w7 = xv[(size_t)(e7.x & 0xffff) * 16 + q];
                acc8(acc, w0, __int_as_float(e0.y));
                acc8(acc, w1, __int_as_float(e1.y));
                acc8(acc, w2, __int_as_float(e2.y));
                acc8(acc, w3, __int_as_float(e3.y));
                acc8(acc, w4, __int_as_float(e4.y));
                acc8(acc, w5, __int_as_float(e5.y));
                acc8(acc, w6, __int_as_float(e6.y));
                acc8(acc, w7, __int_as_float(e7.y));
            }
            for (; p + 2 <= p1; p += 2) {
                int2 e0 = srec[p], e1 = srec[p + 1];
                uint4 w0 = xv[(size_t)(e0.x & 0xffff) * 16 + q];
                uint4 w1 = xv[(size_t)(e1.x & 0xffff) * 16 + q];
                acc8(acc, w0, __int_as_float(e0.y));
                acc8(acc, w1, __int_as_float(e1.y));
            }
            if (p < p1) {
                int2 e = srec[p];
                uint4 w = xv[(size_t)(e.x & 0xffff) * 16 + q];
                acc8(acc, w, __int_as_float(e.y));
            }
            uint4 o;
            o.x = pack2(acc[0], acc[1]);
            o.y = pack2(acc[2], acc[3]);
            o.z = pack2(acc[4], acc[5]);
            o.w = pack2(acc[6], acc[7]);
            *(uint4*)&tile[rl * TSTR + q * 8] = o;
        }
    }
    __syncthreads();

    // MFMA tail: 8 waves x 16-col ntile; rows 50..63 garbage but D row m
    // depends only on A row m; stores guarded.
    int wave = t >> 6, lane = t & 63;
    int m = lane & 15, quad = lane >> 4;
    const bf16x8* bp = (const bf16x8*)Wf;
    bf16x8 bfr[4];
    #pragma unroll
    for (int c = 0; c < 4; ++c) bfr[c] = bp[(wave * 4 + c) * 64 + lane];
    float bcol = bias[wave * 16 + m];

    #pragma unroll
    for (int mt = 0; mt < 4; ++mt) {
        f32x4 acc = {0.f, 0.f, 0.f, 0.f};
        #pragma unroll
        for (int c = 0; c < 4; ++c) {
            bf16x8 afr = *(const bf16x8*)&tile[(mt * 16 + m) * TSTR + c * 32 + quad * 8];
            acc = __builtin_amdgcn_mfma_f32_16x16x32_bf16(afr, bfr[c], acc, 0, 0, 0);
        }
        #pragma unroll
        for (int r = 0; r < 4; ++r) {
            int lr = mt * 16 + quad * 4 + r;
            int grow = rb + lr;
            if (lr < RPB && grow < NN)
                out[(size_t)grow * D + wave * 16 + m] = acc[r] + bcol;
        }
    }
}

extern "C" void kernel_launch(void* const* d_in, const int* in_sizes, int n_in,
                              void* d_out, int out_size, void* d_ws, size_t ws_size,
                              hipStream_t stream) {
    const float* x    = (const float*)d_in[0];
    const float* W    = (const float*)d_in[1];
    const float* bias = (const float*)d_in[2];
    const float* ew   = (const float*)d_in[3];
    const int*   erow = (const int*)d_in[4];
    const int*   ecol = (const int*)d_in[5];
    float* out = (float*)d_out;

    unsigned* ws_u = (unsigned*)d_ws;
    unsigned*        x_h4   = ws_u + XH_OFF;
    unsigned short*  x_h    = (unsigned short*)x_h4;
    unsigned short*  Wf     = (unsigned short*)(ws_u + WF_OFF);
    int*             cursor = (int*)(ws_u + CUR_OFF);
    int2*            recs   = (int2*)(ws_u + REC_OFF);

    hipMemsetAsync(cursor, 0, 1024 * sizeof(int), stream);
    cast_bin_kernel<<<CASTB + PACKB + NBIN, 512, 0, stream>>>(
        x, W, erow, ecol, ew, x_h4, Wf, cursor, recs);
    gat_gemm_kernel<<<NB, 512, 0, stream>>>(x_h, recs, cursor, Wf, bias, out);
}

// Round 10
// 130.617 us; speedup vs baseline: 1.1158x; 1.0477x over previous
//
#include <hip/hip_runtime.h>
#include <hip/hip_bf16.h>

#define NN 50000
#define NE 800000
#define D 128

#define RPB 50            // rows per bucket
#define NB 1000           // NN / RPB
#define NBP 1024          // padded bin count (LDS/scan)
#define CAP 1024          // record capacity per bucket (mean 800, +8 sigma)
#define TILE 4096         // edges per bin block
#define NBIN 196          // ceil(NE/TILE)
#define AROWS 64          // padded rows (4 mtiles x 16)
#define TSTR 136          // bf16 tile row stride (halves): 272B, 16B-aligned

#define CASTB 1563        // ceil(800000 / 512) uint4-casts of x
#define PACKB 4           // 2048 threads / 512

// ws layout in dwords
#define XH_OFF   0                   // x_h bf16: 3,200,000 dwords
#define WF_OFF   3200000             // Wf: 8192 dwords
#define CUR_OFF  3208192             // NBP cursors
#define REC_OFF  3209216             // records: NB*CAP int2 = 2,048,000 dwords

typedef short bf16x8 __attribute__((ext_vector_type(8)));
typedef float f32x4 __attribute__((ext_vector_type(4)));

__device__ inline unsigned short f2bf_u(float f) {
    __hip_bfloat16 h = __float2bfloat16(f);   // RNE
    return __builtin_bit_cast(unsigned short, h);
}
__device__ inline unsigned pack2(float a, float b) {
    return (unsigned)f2bf_u(a) | ((unsigned)f2bf_u(b) << 16);
}
__device__ inline void acc8(float* acc, uint4 v, float w) {
    unsigned dw[4] = {v.x, v.y, v.z, v.w};
    #pragma unroll
    for (int i = 0; i < 4; ++i) {
        float lo = __int_as_float((int)(dw[i] << 16));
        float hi = __int_as_float((int)(dw[i] & 0xffff0000u));
        acc[2 * i]     += w * lo;
        acc[2 * i + 1] += w * hi;
    }
}

// ---------------------------------------------------------------------------
// 1) fused grid: [0,CASTB) cast x->bf16 | [..+PACKB) pack W B-frag |
//    [..+NBIN) bin edges into 1000 coarse buckets via LDS staging.
//    cursor[] zeroed by a prior hipMemsetAsync.
// ---------------------------------------------------------------------------
__global__ __launch_bounds__(512) void cast_bin_kernel(
    const float* __restrict__ x, const float* __restrict__ W,
    const int* __restrict__ erow, const int* __restrict__ ecol,
    const float* __restrict__ ew,
    unsigned* __restrict__ x_h4, unsigned short* __restrict__ Wf,
    int* __restrict__ cursor, int2* __restrict__ recs)
{
    __shared__ int  lhist[NBP];
    __shared__ int  lexcl[NBP];
    __shared__ int  lbase[NBP];
    __shared__ int  lpair[512];
    __shared__ int2 stag[TILE];

    int b = blockIdx.x;
    int t = threadIdx.x;

    if (b < CASTB) {
        int idx = b * 512 + t;                 // [0, 800000)
        if (idx < 800000) {
            const float4* x4 = (const float4*)x;
            float4 v0 = x4[idx * 2];
            float4 v1 = x4[idx * 2 + 1];
            uint4 o;
            o.x = pack2(v0.x, v0.y);
            o.y = pack2(v0.z, v0.w);
            o.z = pack2(v1.x, v1.y);
            o.w = pack2(v1.z, v1.w);
            ((uint4*)x_h4)[idx] = o;
        }
        return;
    }
    if (b < CASTB + PACKB) {
        // Wf[(nt*4+c)*64+lane] : element j -> W[c*32+(lane>>4)*8+j][nt*16+(lane&15)]
        int flat = (b - CASTB) * 512 + t;      // [0, 2048)
        int lane = flat & 63;
        int c    = (flat >> 6) & 3;
        int nt   = flat >> 8;
        int col  = nt * 16 + (lane & 15);
        int kb   = c * 32 + (lane >> 4) * 8;
        unsigned d[4];
        #pragma unroll
        for (int jj = 0; jj < 4; ++jj) {
            float a  = W[(kb + 2 * jj) * D + col];
            float bb = W[(kb + 2 * jj + 1) * D + col];
            d[jj] = pack2(a, bb);
        }
        uint4 o; o.x = d[0]; o.y = d[1]; o.z = d[2]; o.w = d[3];
        ((uint4*)Wf)[flat] = o;
        return;
    }

    // ---- bin branch ----
    int base = (b - CASTB - PACKB) * TILE;
    int cnt = NE - base; if (cnt > TILE) cnt = TILE;

    lhist[t] = 0;
    lhist[t + 512] = 0;
    __syncthreads();

    int4 r[2], c[2]; float4 w[2]; bool val[2];
    #pragma unroll
    for (int g = 0; g < 2; ++g) {
        int i4 = (base >> 2) + t + g * 512;
        val[g] = (i4 * 4) < NE && (i4 * 4) < (base + TILE);
        if (val[g]) {
            r[g] = ((const int4*)erow)[i4];
            c[g] = ((const int4*)ecol)[i4];
            w[g] = ((const float4*)ew)[i4];
        }
    }
    #pragma unroll
    for (int g = 0; g < 2; ++g) {
        if (val[g]) {
            atomicAdd(&lhist[(unsigned)r[g].x / RPB], 1);
            atomicAdd(&lhist[(unsigned)r[g].y / RPB], 1);
            atomicAdd(&lhist[(unsigned)r[g].z / RPB], 1);
            atomicAdd(&lhist[(unsigned)r[g].w / RPB], 1);
        }
    }
    __syncthreads();

    // scan 1024 bins with 512 threads (pair-sum + Hillis-Steele)
    int a0 = lhist[2 * t], a1 = lhist[2 * t + 1];
    lpair[t] = a0 + a1;
    __syncthreads();
    for (int off = 1; off < 512; off <<= 1) {
        int v = (t >= off) ? lpair[t - off] : 0;
        __syncthreads();
        lpair[t] += v;
        __syncthreads();
    }
    int exclp = lpair[t] - (a0 + a1);
    lexcl[2 * t]     = exclp;
    lexcl[2 * t + 1] = exclp + a0;
    lbase[2 * t]     = a0 ? atomicAdd(&cursor[2 * t], a0) : 0;
    lbase[2 * t + 1] = a1 ? atomicAdd(&cursor[2 * t + 1], a1) : 0;
    lhist[2 * t]     = exclp;          // rank cursor
    lhist[2 * t + 1] = exclp + a0;
    __syncthreads();

    #pragma unroll
    for (int g = 0; g < 2; ++g) {
        if (val[g]) {
            int rr[4] = {r[g].x, r[g].y, r[g].z, r[g].w};
            int cc[4] = {c[g].x, c[g].y, c[g].z, c[g].w};
            float wwv[4] = {w[g].x, w[g].y, w[g].z, w[g].w};
            #pragma unroll
            for (int j = 0; j < 4; ++j) {
                int bk = (unsigned)rr[j] / RPB;
                int rank = atomicAdd(&lhist[bk], 1);
                int2 rec;
                rec.x = (rr[j] << 16) | cc[j];
                rec.y = __float_as_int(wwv[j]);
                stag[rank] = rec;
            }
        }
    }
    __syncthreads();

    #pragma unroll
    for (int k = 0; k < 8; ++k) {
        int i = t + k * 512;
        if (i < cnt) {
            int2 rec = stag[i];
            int bk = (((unsigned)rec.x) >> 16) / RPB;
            int pos = lbase[bk] + (i - lexcl[bk]);
            if (pos < CAP)
                recs[(size_t)bk * CAP + pos] = rec;
        }
    }
}

// ---------------------------------------------------------------------------
// 2) per-bucket (50 rows): records -> LDS counting-sort by row -> single-row
//    register gather (16 lanes/node, unroll 4) -> bf16 LDS tile ->
//    MFMA GEMM + bias -> out. __launch_bounds__(512,4) pins VGPR<=128 so
//    2 blocks/CU stay resident (R9: unroll-8 spilled past this and regressed).
// ---------------------------------------------------------------------------
__global__ __launch_bounds__(512, 4) void gat_gemm_kernel(
    const unsigned short* __restrict__ x_h, const int2* __restrict__ recs,
    const int* __restrict__ cursor, const unsigned short* __restrict__ Wf,
    const float* __restrict__ bias, float* __restrict__ out)
{
    __shared__ int2 srec[CAP];                                   // 8 KB
    __shared__ __align__(16) unsigned short tile[AROWS * TSTR];  // 17.4 KB
    __shared__ int rowstart[RPB + 1];
    __shared__ int rowcur[64];
    __shared__ int stmp[64];

    int t = threadIdx.x;
    int b = blockIdx.x;
    int cnt = cursor[b];
    if (cnt > CAP) cnt = CAP;
    int rb = b * RPB;
    const int2* my = recs + (size_t)b * CAP;

    if (t < 64) rowcur[t] = 0;
    __syncthreads();

    // single global pass: records -> registers
    int2 r0, r1;
    bool v0 = t < cnt, v1 = t + 512 < cnt;
    if (v0) r0 = my[t];
    if (v1) r1 = my[t + 512];

    if (v0) atomicAdd(&rowcur[(((unsigned)r0.x) >> 16) - rb], 1);
    if (v1) atomicAdd(&rowcur[(((unsigned)r1.x) >> 16) - rb], 1);
    __syncthreads();

    // exclusive scan of 50 row counts (first 64 threads)
    int myc = 0;
    if (t < 64) { myc = rowcur[t]; stmp[t] = myc; }
    __syncthreads();
    for (int off = 1; off < 64; off <<= 1) {
        int v = 0;
        if (t < 64 && t >= off) v = stmp[t - off];
        __syncthreads();
        if (t < 64) stmp[t] += v;
        __syncthreads();
    }
    if (t < 64) { int ex = stmp[t] - myc; if (t <= RPB) rowstart[t] = ex; rowcur[t] = ex; }
    if (t == 0) rowstart[RPB] = cnt;
    __syncthreads();

    // rank + scatter into srec (sorted by row)
    if (v0) srec[atomicAdd(&rowcur[(((unsigned)r0.x) >> 16) - rb], 1)] = r0;
    if (v1) srec[atomicAdd(&rowcur[(((unsigned)r1.x) >> 16) - rb], 1)] = r1;
    __syncthreads();

    // gather: 16 lanes per node, 32 nodes concurrently, unroll 4
    int q = t & 15;
    int grp = t >> 4;
    const uint4* xv = (const uint4*)x_h;   // one x row = 16 uint4
    #pragma unroll
    for (int it = 0; it < 2; ++it) {
        int rl = it * 32 + grp;
        if (rl < RPB) {
            int p = rowstart[rl], p1 = rowstart[rl + 1];
            float acc[8] = {};
            for (; p + 4 <= p1; p += 4) {
                int2 e0 = srec[p];
                int2 e1 = srec[p + 1];
                int2 e2 = srec[p + 2];
                int2 e3 = srec[p + 3];
                uint4 w0 = xv[(size_t)(e0.x & 0xffff) * 16 + q];
                uint4 w1 = xv[(size_t)(e1.x & 0xffff) * 16 + q];
                uint4 w2 = xv[(size_t)(e2.x & 0xffff) * 16 + q];
                uint4 w3 = xv[(size_t)(e3.x & 0xffff) * 16 + q];
                acc8(acc, w0, __int_as_float(e0.y));
                acc8(acc, w1, __int_as_float(e1.y));
                acc8(acc, w2, __int_as_float(e2.y));
                acc8(acc, w3, __int_as_float(e3.y));
            }
            for (; p < p1; ++p) {
                int2 e = srec[p];
                uint4 w = xv[(size_t)(e.x & 0xffff) * 16 + q];
                acc8(acc, w, __int_as_float(e.y));
            }
            uint4 o;
            o.x = pack2(acc[0], acc[1]);
            o.y = pack2(acc[2], acc[3]);
            o.z = pack2(acc[4], acc[5]);
            o.w = pack2(acc[6], acc[7]);
            *(uint4*)&tile[rl * TSTR + q * 8] = o;
        }
    }
    __syncthreads();

    // MFMA tail: 8 waves x (16-col ntile); rows 50..63 garbage but D row m
    // depends only on A row m; stores guarded.
    int wave = t >> 6, lane = t & 63;
    int m = lane & 15, quad = lane >> 4;
    const bf16x8* bp = (const bf16x8*)Wf;
    bf16x8 bfr[4];
    #pragma unroll
    for (int c = 0; c < 4; ++c) bfr[c] = bp[(wave * 4 + c) * 64 + lane];
    float bcol = bias[wave * 16 + m];

    #pragma unroll
    for (int mt = 0; mt < 4; ++mt) {
        f32x4 acc = {0.f, 0.f, 0.f, 0.f};
        #pragma unroll
        for (int c = 0; c < 4; ++c) {
            bf16x8 afr = *(const bf16x8*)&tile[(mt * 16 + m) * TSTR + c * 32 + quad * 8];
            acc = __builtin_amdgcn_mfma_f32_16x16x32_bf16(afr, bfr[c], acc, 0, 0, 0);
        }
        #pragma unroll
        for (int r = 0; r < 4; ++r) {
            int lr = mt * 16 + quad * 4 + r;
            int grow = rb + lr;
            if (lr < RPB && grow < NN)
                out[(size_t)grow * D + wave * 16 + m] = acc[r] + bcol;
        }
    }
}

extern "C" void kernel_launch(void* const* d_in, const int* in_sizes, int n_in,
                              void* d_out, int out_size, void* d_ws, size_t ws_size,
                              hipStream_t stream) {
    const float* x    = (const float*)d_in[0];
    const float* W    = (const float*)d_in[1];
    const float* bias = (const float*)d_in[2];
    const float* ew   = (const float*)d_in[3];
    const int*   erow = (const int*)d_in[4];
    const int*   ecol = (const int*)d_in[5];
    float* out = (float*)d_out;

    unsigned* ws_u = (unsigned*)d_ws;
    unsigned*        x_h4   = ws_u + XH_OFF;
    unsigned short*  x_h    = (unsigned short*)x_h4;
    unsigned short*  Wf     = (unsigned short*)(ws_u + WF_OFF);
    int*             cursor = (int*)(ws_u + CUR_OFF);
    int2*            recs   = (int2*)(ws_u + REC_OFF);

    hipMemsetAsync(cursor, 0, NBP * sizeof(int), stream);
    cast_bin_kernel<<<CASTB + PACKB + NBIN, 512, 0, stream>>>(
        x, W, erow, ecol, ew, x_h4, Wf, cursor, recs);
    gat_gemm_kernel<<<NB, 512, 0, stream>>>(x_h, recs, cursor, Wf, bias, out);
}